// Round 9
// baseline (334.687 us; speedup 1.0000x reference)
//
#include <hip/hip_runtime.h>
#include <hip/hip_bf16.h>
#include <stdint.h>

// Problem constants: B=64, L=96, C=32, H=256, NL=2, K=3, TAU=2, VTH=1
// n = b*32 + c indexes the B*C=2048 "rows"; layer width H=256.

using floatx4 = __attribute__((ext_vector_type(4))) float;
using intx4   = __attribute__((ext_vector_type(4))) int;

// ---------------------------------------------------------------------------
// prep: per output-neuron o (256 blocks x 64 threads)
//  - W[o][k]  = sum_i w0[o,i]*w_enc[i,k]   (fp64)
//  - C0[o]    = sum_i b_enc[i]*w0[o,i] + b_rnn[0][o]  (fp64)
//  - i8 4-limb digit planes of w1: q=rn(w*2^27), q=((d0*128+d1)*128+d2)*128+d3,
//    digits in [-64,63]. Bw8[o][l][k] = d_l of w1[o][k]. EXACT (|w|<1).
// ---------------------------------------------------------------------------
__global__ void prep_kernel(const float* __restrict__ w_enc,
                            const float* __restrict__ b_enc,
                            const float* __restrict__ w_rnn,
                            const float* __restrict__ b_rnn,
                            double* __restrict__ Wd,
                            double* __restrict__ C0d,
                            signed char* __restrict__ Bw8)
{
    const int o = blockIdx.x;
    const int lane = threadIdx.x;   // 64 threads
    const float4 w0v = *(const float4*)(w_rnn + (size_t)o * 256 + lane * 4);
    double a0 = 0.0, a1 = 0.0, a2 = 0.0, ab = 0.0;
#pragma unroll
    for (int e = 0; e < 4; ++e) {
        const int i = lane * 4 + e;
        const double wv = (double)(((const float*)&w0v)[e]);
        a0 += wv * (double)w_enc[i * 3 + 0];
        a1 += wv * (double)w_enc[i * 3 + 1];
        a2 += wv * (double)w_enc[i * 3 + 2];
        ab += wv * (double)b_enc[i];
    }
    for (int off = 32; off > 0; off >>= 1) {
        a0 += __shfl_down(a0, off, 64);
        a1 += __shfl_down(a1, off, 64);
        a2 += __shfl_down(a2, off, 64);
        ab += __shfl_down(ab, off, 64);
    }
    if (lane == 0) {
        Wd[o * 3 + 0] = a0;
        Wd[o * 3 + 1] = a1;
        Wd[o * 3 + 2] = a2;
        C0d[o] = ab + (double)b_rnn[o];
    }
    // i8 digit planes of w1 (layer-1), 4 consecutive k per lane
    const float4 w1v = *(const float4*)(w_rnn + 65536 + (size_t)o * 256 + lane * 4);
    unsigned int pack[4] = {0u, 0u, 0u, 0u};   // pack[l]: digits for e=0..3
#pragma unroll
    for (int e = 0; e < 4; ++e) {
        float f = ((const float*)&w1v)[e];
        int q = __double2int_rn((double)f * 134217728.0);   // w * 2^27, |q| <= 2^27
        int d3 = ((q + 64) & 127) - 64;  q = (q - d3) >> 7;
        int d2 = ((q + 64) & 127) - 64;  q = (q - d2) >> 7;
        int d1 = ((q + 64) & 127) - 64;  q = (q - d1) >> 7;
        int d0 = q;                       // |d0| <= 64
        pack[0] |= ((unsigned int)(d0 & 0xFF)) << (8 * e);
        pack[1] |= ((unsigned int)(d1 & 0xFF)) << (8 * e);
        pack[2] |= ((unsigned int)(d2 & 0xFF)) << (8 * e);
        pack[3] |= ((unsigned int)(d3 & 0xFF)) << (8 * e);
    }
#pragma unroll
    for (int l = 0; l < 4; ++l)
        *(unsigned int*)(Bw8 + ((size_t)o * 4 + l) * 256 + lane * 4) = pack[l];
}

// ---------------------------------------------------------------------------
// enc: layer-0 full scan. 2048 blocks x 256 threads. cur0 in fp64 (correctly
// rounded), membrane chain in exact reference fp32 op order. Spike mask rows
// stored HALFWORD-TRANSPOSED: row (t,n) is 32B; global halfword h=i/16
// (h = 4*wave + j) lands at byte offset 8*j + 2*wave -> rnn lane (g,m) reads
// one aligned uint2 at +8g = exactly the k-bits its 4 MFMA chunks need.
// ---------------------------------------------------------------------------
__global__ void enc_kernel(const float* __restrict__ inputs,
                           const double* __restrict__ Wd,
                           const double* __restrict__ C0d,
                           unsigned char* __restrict__ s0b)
{
    const int n = blockIdx.x;
    const int tidx = threadIdx.x;
    const int b = n >> 5, c = n & 31;
    __shared__ float xr[98];
    if (tidx < 96)       xr[tidx + 1] = inputs[((size_t)b * 96 + tidx) * 32 + c];
    else if (tidx == 96) xr[0]  = 0.0f;
    else if (tidx == 97) xr[97] = 0.0f;
    __syncthreads();
    const double W0 = Wd[tidx * 3], W1 = Wd[tidx * 3 + 1], W2 = Wd[tidx * 3 + 2];
    const double c0 = C0d[tidx];
    const int wid = tidx >> 6, lane = tidx & 63;
    float v = 0.0f;
    for (int t = 0; t < 96; ++t) {
        float cur = (float)((double)xr[t] * W0 + (double)xr[t + 1] * W1 +
                            (double)xr[t + 2] * W2 + c0);
        float vv = v + (cur - v) * 0.5f;
        int sp = (vv - 1.0f) >= 0.0f;
        v = sp ? 0.0f : vv;
        unsigned long long bal = __ballot(sp);
        if ((lane & 15) == 0) {
            const int j = lane >> 4;
            *(unsigned short*)(s0b + ((size_t)t * 2048 + n) * 32 + 8 * j + 2 * wid)
                = (unsigned short)(bal >> (16 * j));
        }
    }
}

// ---------------------------------------------------------------------------
// rnn: layer-1, i8 4-limb exact MFMA, NO LDS, NO barriers, and (R9) NO
// scattered out0 writes: spikes leave as NIBBLE-BYTES into s1b (12.6 MB),
// one contiguous 64B run per wave per step -> rnn is no longer paced by the
// 201MB scatter-write pattern. s1b layout: byte = s1b[t][jo][n][g] at offset
// t*131072 + jo*8192 + n*4 + g; bit r of byte = spike(row n, col 16jo+4g+r).
// Each 64B line is written by exactly one wave (no false sharing).
// 2048 wave-jobs (512 blocks x 4 waves); wave = 16 rows x 16 cols.
// Decision math BIT-IDENTICAL to R8 (i8 limbs + fp32 exact combine;
// v-update sp?0:vv == vv*(1-s) for s in {0,1}).
// ---------------------------------------------------------------------------
__global__ __launch_bounds__(256, 2) void rnn_kernel(
    const unsigned char* __restrict__ s0b,
    const signed char* __restrict__ Bw8,
    const float* __restrict__ b_rnn,
    unsigned char* __restrict__ s1b)
{
    const int tid  = threadIdx.x;
    const int wid  = tid >> 6, lane = tid & 63;
    const int m    = lane & 15, g = lane >> 4;
    const int job  = blockIdx.x * 4 + wid;          // 2048 jobs
    const int rt   = job >> 4;                      // 128 row-tiles
    const int nw   = rt * 16;
    const int jo   = job & 15;                      // 16 col-tiles
    const int o0   = jo * 16;

    // --- weight A-fragments (loop-invariant): 4 limbs x 4 chunks = 64 VGPRs
    intx4 bfrag[4][4];
#pragma unroll
    for (int l = 0; l < 4; ++l)
#pragma unroll
        for (int c = 0; c < 4; ++c)
            bfrag[l][c] = *(const intx4*)(Bw8 + ((size_t)(o0 + m) * 4 + l) * 256
                                               + c * 64 + g * 16);
    // per-lane bias for out-cols o0+4g .. o0+4g+3
    const float4 biasv = *(const float4*)(b_rnn + 256 + o0 + g * 4);

    // --- spike-byte store base: s1b[t][jo][nw+m][g] ---
    unsigned char* sp_ptr = s1b + (size_t)jo * 8192 + (size_t)(nw + m) * 4 + g;

    // --- mask stream: lane reads uint2 at row*32 + 8g, prefetched 2 ahead ---
    const unsigned char* mp = s0b + ((size_t)(nw + m)) * 32 + 8 * g;
    uint2 m0 = *(const uint2*)(mp);
    uint2 m1 = *(const uint2*)(mp + 65536);

    floatx4 v = {0.f, 0.f, 0.f, 0.f};

    for (int t = 0; t < 96; ++t) {
        uint2 nxt = m1;
        m1 = *(const uint2*)(mp + (size_t)(t + 2) * 65536);   // slots 96/97 padded

        intx4 acc0 = {0,0,0,0}, acc1 = {0,0,0,0}, acc2 = {0,0,0,0}, acc3 = {0,0,0,0};
        {
            unsigned int hw_[4] = { m0.x & 0xFFFFu, m0.x >> 16,
                                    m0.y & 0xFFFFu, m0.y >> 16 };
#pragma unroll
            for (int c = 0; c < 4; ++c) {
                unsigned int h_ = hw_[c];
                intx4 a_;
                a_.x = (int)((( h_        & 0xFu) * 0x00204081u) & 0x01010101u);
                a_.y = (int)((((h_ >> 4)  & 0xFu) * 0x00204081u) & 0x01010101u);
                a_.z = (int)((((h_ >> 8)  & 0xFu) * 0x00204081u) & 0x01010101u);
                a_.w = (int)((((h_ >> 12) & 0xFu) * 0x00204081u) & 0x01010101u);
                acc0 = __builtin_amdgcn_mfma_i32_16x16x64_i8(bfrag[0][c], a_, acc0, 0, 0, 0);
                acc1 = __builtin_amdgcn_mfma_i32_16x16x64_i8(bfrag[1][c], a_, acc1, 0, 0, 0);
                acc2 = __builtin_amdgcn_mfma_i32_16x16x64_i8(bfrag[2][c], a_, acc2, 0, 0, 0);
                acc3 = __builtin_amdgcn_mfma_i32_16x16x64_i8(bfrag[3][c], a_, acc3, 0, 0, 0);
            }
        }

        // exact fp32 limb combine + membrane update (reference fp32 op order)
        unsigned int nib = 0u;
#pragma unroll
        for (int r = 0; r < 4; ++r) {
            int a01 = acc0[r] * 128 + acc1[r];      // exact, |.| < 2^22
            int a23 = acc2[r] * 128 + acc3[r];
            float cur = fmaf((float)a01, 0x1p-13f, (float)a23 * 0x1p-27f)
                        + ((const float*)&biasv)[r];
            float vv = v[r];
            vv = vv + (cur - vv) * 0.5f;
            bool sp = (vv - 1.0f) >= 0.0f;
            nib |= sp ? (1u << r) : 0u;
            v[r] = sp ? 0.0f : vv;                  // == vv*(1-s), s in {0,1}
        }
        sp_ptr[(size_t)t * 131072] = (unsigned char)nib;
        m0 = nxt;
    }
}

// ---------------------------------------------------------------------------
// expand: streaming materialization of out0 (201MB) + out1 (2MB) from s1b.
// 2048 blocks x 256 threads, 6 grid-stride iters; each thread-iter owns a
// contiguous 64B run of out0 (4 x float4), consecutive lanes contiguous ->
// the exact streaming pattern the 6.6 TB/s fill achieves. Reads: one aligned
// u32 of 4 nibble-bytes per 64B written (12.6MB total, L2-friendly).
// ---------------------------------------------------------------------------
__global__ void expand_kernel(const unsigned char* __restrict__ s1b,
                              float* __restrict__ out0,
                              float* __restrict__ out1)
{
    const unsigned int tid0 = blockIdx.x * 256u + threadIdx.x;   // 524288 threads
#pragma unroll
    for (int it = 0; it < 6; ++it) {
        const unsigned int gi = tid0 + (unsigned int)it * 524288u; // f4-group id
        const unsigned int bt = gi >> 9;            // b*96 + t
        const unsigned int b  = bt / 96u;
        const unsigned int t  = bt - b * 96u;
        const unsigned int cc = (gi >> 4) & 31u;
        const unsigned int k  = (gi * 4u) & 63u;    // col-group base (mult of 4)
        const unsigned int n  = b * 32u + cc;
        const unsigned int quad = *(const unsigned int*)(s1b
                + (size_t)t * 131072u + (size_t)(k >> 2) * 8192u + (size_t)n * 4u);
        float* po = out0 + (size_t)gi * 16u;
        const bool last = (t == 95u);
        float* p1 = out1 + (size_t)b * 8192u + (size_t)cc * 256u + (size_t)k * 4u;
#pragma unroll
        for (int j = 0; j < 4; ++j) {
            const unsigned int nib = (quad >> (8 * j)) & 0xFu;
            float4 w;
            w.x = (float)( nib        & 1u);
            w.y = (float)((nib >> 1u) & 1u);
            w.z = (float)((nib >> 2u) & 1u);
            w.w = (float)((nib >> 3u) & 1u);
            *(float4*)(po + 4 * j) = w;
            if (last) *(float4*)(p1 + 4 * j) = w;
        }
    }
}

// ---------------------------------------------------------------------------
extern "C" void kernel_launch(void* const* d_in, const int* in_sizes, int n_in,
                              void* d_out, int out_size, void* d_ws, size_t ws_size,
                              hipStream_t stream) {
    const float* inputs = (const float*)d_in[0];   // [64,96,32]
    const float* w_enc  = (const float*)d_in[1];   // [256,1,3]
    const float* b_enc  = (const float*)d_in[2];   // [256]
    const float* w_rnn  = (const float*)d_in[3];   // [2,256,256]
    const float* b_rnn  = (const float*)d_in[4];   // [2,256]

    float* out0 = (float*)d_out;                       // [64,96,8192]
    float* out1 = out0 + (size_t)64 * 96 * 8192;       // [64,8192]

    char* ws = (char*)d_ws;
    double*        Wd  = (double*)(ws);                //  768 doubles  [0,6144)
    double*        C0d = (double*)(ws + 6144);         //  256 doubles  [6144,8192)
    signed char*   Bw8 = (signed char*)(ws + 8192);    //  256*4*256 i8 [8192,270336)
    unsigned char* s0b = (unsigned char*)(ws + 270336);// 98*65536 B layer-0 spike bits
    unsigned char* s1b = s0b + (size_t)98 * 65536;     // 96*131072 B layer-1 nibbles

    prep_kernel<<<256, 64, 0, stream>>>(w_enc, b_enc, w_rnn, b_rnn, Wd, C0d, Bw8);
    enc_kernel<<<2048, 256, 0, stream>>>(inputs, Wd, C0d, s0b);
    rnn_kernel<<<512, 256, 0, stream>>>(s0b, Bw8, b_rnn, s1b);
    expand_kernel<<<2048, 256, 0, stream>>>(s1b, out0, out1);
}

// Round 10
// 297.192 us; speedup vs baseline: 1.1262x; 1.1262x over previous
//
#include <hip/hip_runtime.h>
#include <hip/hip_bf16.h>
#include <stdint.h>

// Problem constants: B=64, L=96, C=32, H=256, NL=2, K=3, TAU=2, VTH=1
// n = b*32 + c indexes the B*C=2048 "rows"; layer width H=256.

using floatx4 = __attribute__((ext_vector_type(4))) float;
using intx4   = __attribute__((ext_vector_type(4))) int;

// ---------------------------------------------------------------------------
// prep: per output-neuron o (256 blocks x 64 threads)
//  - W[o][k]  = sum_i w0[o,i]*w_enc[i,k]   (fp64)
//  - C0[o]    = sum_i b_enc[i]*w0[o,i] + b_rnn[0][o]  (fp64)
//  - i8 4-limb digit planes of w1: q=rn(w*2^27), q=((d0*128+d1)*128+d2)*128+d3,
//    digits in [-64,63]. Bw8[o][l][k] = d_l of w1[o][k]. EXACT (|w|<1).
// ---------------------------------------------------------------------------
__global__ void prep_kernel(const float* __restrict__ w_enc,
                            const float* __restrict__ b_enc,
                            const float* __restrict__ w_rnn,
                            const float* __restrict__ b_rnn,
                            double* __restrict__ Wd,
                            double* __restrict__ C0d,
                            signed char* __restrict__ Bw8)
{
    const int o = blockIdx.x;
    const int lane = threadIdx.x;   // 64 threads
    const float4 w0v = *(const float4*)(w_rnn + (size_t)o * 256 + lane * 4);
    double a0 = 0.0, a1 = 0.0, a2 = 0.0, ab = 0.0;
#pragma unroll
    for (int e = 0; e < 4; ++e) {
        const int i = lane * 4 + e;
        const double wv = (double)(((const float*)&w0v)[e]);
        a0 += wv * (double)w_enc[i * 3 + 0];
        a1 += wv * (double)w_enc[i * 3 + 1];
        a2 += wv * (double)w_enc[i * 3 + 2];
        ab += wv * (double)b_enc[i];
    }
    for (int off = 32; off > 0; off >>= 1) {
        a0 += __shfl_down(a0, off, 64);
        a1 += __shfl_down(a1, off, 64);
        a2 += __shfl_down(a2, off, 64);
        ab += __shfl_down(ab, off, 64);
    }
    if (lane == 0) {
        Wd[o * 3 + 0] = a0;
        Wd[o * 3 + 1] = a1;
        Wd[o * 3 + 2] = a2;
        C0d[o] = ab + (double)b_rnn[o];
    }
    // i8 digit planes of w1 (layer-1), 4 consecutive k per lane
    const float4 w1v = *(const float4*)(w_rnn + 65536 + (size_t)o * 256 + lane * 4);
    unsigned int pack[4] = {0u, 0u, 0u, 0u};   // pack[l]: digits for e=0..3
#pragma unroll
    for (int e = 0; e < 4; ++e) {
        float f = ((const float*)&w1v)[e];
        int q = __double2int_rn((double)f * 134217728.0);   // w * 2^27, |q| <= 2^27
        int d3 = ((q + 64) & 127) - 64;  q = (q - d3) >> 7;
        int d2 = ((q + 64) & 127) - 64;  q = (q - d2) >> 7;
        int d1 = ((q + 64) & 127) - 64;  q = (q - d1) >> 7;
        int d0 = q;                       // |d0| <= 64
        pack[0] |= ((unsigned int)(d0 & 0xFF)) << (8 * e);
        pack[1] |= ((unsigned int)(d1 & 0xFF)) << (8 * e);
        pack[2] |= ((unsigned int)(d2 & 0xFF)) << (8 * e);
        pack[3] |= ((unsigned int)(d3 & 0xFF)) << (8 * e);
    }
#pragma unroll
    for (int l = 0; l < 4; ++l)
        *(unsigned int*)(Bw8 + ((size_t)o * 4 + l) * 256 + lane * 4) = pack[l];
}

// ---------------------------------------------------------------------------
// enc: layer-0 full scan. 2048 blocks x 256 threads. cur0 in fp64 (correctly
// rounded), membrane chain in exact reference fp32 op order. R10: spikes are
// written as 0/1 BYTES, s0B[t][n][o] (50 MB, L3-resident) — each block writes
// 256 contiguous bytes per step (full 64B lines per wave). This removes the
// bit->byte expansion from rnn's hot loop entirely.
// ---------------------------------------------------------------------------
__global__ void enc_kernel(const float* __restrict__ inputs,
                           const double* __restrict__ Wd,
                           const double* __restrict__ C0d,
                           unsigned char* __restrict__ s0B)
{
    const int n = blockIdx.x;
    const int tidx = threadIdx.x;
    const int b = n >> 5, c = n & 31;
    __shared__ float xr[98];
    if (tidx < 96)       xr[tidx + 1] = inputs[((size_t)b * 96 + tidx) * 32 + c];
    else if (tidx == 96) xr[0]  = 0.0f;
    else if (tidx == 97) xr[97] = 0.0f;
    __syncthreads();
    const double W0 = Wd[tidx * 3], W1 = Wd[tidx * 3 + 1], W2 = Wd[tidx * 3 + 2];
    const double c0 = C0d[tidx];
    unsigned char* po = s0B + (size_t)n * 256 + tidx;
    float v = 0.0f;
    for (int t = 0; t < 96; ++t) {
        float cur = (float)((double)xr[t] * W0 + (double)xr[t + 1] * W1 +
                            (double)xr[t + 2] * W2 + c0);
        float vv = v + (cur - v) * 0.5f;
        int sp = (vv - 1.0f) >= 0.0f;
        v = sp ? 0.0f : vv;
        po[(size_t)t * 524288] = (unsigned char)sp;
    }
}

// ---------------------------------------------------------------------------
// rnn: layer-1, i8 4-limb exact MFMA, NO LDS, NO barriers, NO bit expansion.
// 2048 wave-jobs (512 blocks x 4 waves); wave = 16 rows x 16 cols; the 4
// waves of a block share the same 16 rows (75% L1 hits on spike reads).
// Per step: B-operand (spikes) loaded DIRECTLY as 4x dwordx4 per lane —
// 16 consecutive neuron-bytes at s0B[t][nw+m][64c+16g] is exactly the i8
// B-fragment (k = 64c + 16g + j), matching the weight A-fragment packing.
// Single-step prefetch hides L1/L2 latency. Weights in the A slot (R8 swap)
// -> lane (g,m) holds 4 consecutive out-cols of spike-row nw+m -> one
// global_store_dwordx4 per step, each 64B out0 line fully covered by one
// store instruction (lanes m, m+16, m+32, m+48).
// Decision math BIT-IDENTICAL to R8: i8 limb MFMA (exact), fp32 limb combine
// fmaf((float)a01, 2^-13, (float)a23*2^-27) == RN(exact sum); membrane in
// exact reference fp32 op order; sp?0:vv == vv*(1-s) for s in {0,1}.
// ---------------------------------------------------------------------------
__global__ __launch_bounds__(256, 2) void rnn_kernel(
    const unsigned char* __restrict__ s0B,
    const signed char* __restrict__ Bw8,
    const float* __restrict__ b_rnn,
    float* __restrict__ out0,
    float* __restrict__ out1)
{
    const int tid  = threadIdx.x;
    const int wid  = tid >> 6, lane = tid & 63;
    const int m    = lane & 15, g = lane >> 4;
    const int job  = blockIdx.x * 4 + wid;          // 2048 jobs
    const int rt   = job >> 4;                      // 128 row-tiles
    const int nw   = rt * 16;
    const int o0   = (job & 15) * 16;               // 16 col-tiles

    // --- weight A-fragments (loop-invariant): 4 limbs x 4 chunks = 64 VGPRs
    intx4 bfrag[4][4];
#pragma unroll
    for (int l = 0; l < 4; ++l)
#pragma unroll
        for (int c = 0; c < 4; ++c)
            bfrag[l][c] = *(const intx4*)(Bw8 + ((size_t)(o0 + m) * 4 + l) * 256
                                               + c * 64 + g * 16);
    // per-lane bias for out-cols o0+4g .. o0+4g+3
    const float4 biasv = *(const float4*)(b_rnn + 256 + o0 + g * 4);

    // --- store base: spike-row nw+m, col o0+4g (16B-aligned) ---
    float* pb = out0 + ((size_t)(nw >> 5) * 96) * 8192
                     + (size_t)((nw & 31) + m) * 256 + o0 + g * 4;

    // --- spike byte stream: lane reads 4x16B at row*256 + 64c + 16g ---
    const unsigned char* sp_base = s0B + (size_t)(nw + m) * 256 + 16 * g;
    uint4 cb0 = *(const uint4*)(sp_base);
    uint4 cb1 = *(const uint4*)(sp_base + 64);
    uint4 cb2 = *(const uint4*)(sp_base + 128);
    uint4 cb3 = *(const uint4*)(sp_base + 192);

    floatx4 v = {0.f, 0.f, 0.f, 0.f};

    #define STEP_MFMA(B0, B1, B2, B3, ACC0, ACC1, ACC2, ACC3)                  \
    do {                                                                       \
        intx4 a0_ = *(intx4*)&(B0), a1_ = *(intx4*)&(B1),                      \
              a2_ = *(intx4*)&(B2), a3_ = *(intx4*)&(B3);                      \
        ACC0 = __builtin_amdgcn_mfma_i32_16x16x64_i8(bfrag[0][0], a0_, ACC0, 0, 0, 0); \
        ACC1 = __builtin_amdgcn_mfma_i32_16x16x64_i8(bfrag[1][0], a0_, ACC1, 0, 0, 0); \
        ACC2 = __builtin_amdgcn_mfma_i32_16x16x64_i8(bfrag[2][0], a0_, ACC2, 0, 0, 0); \
        ACC3 = __builtin_amdgcn_mfma_i32_16x16x64_i8(bfrag[3][0], a0_, ACC3, 0, 0, 0); \
        ACC0 = __builtin_amdgcn_mfma_i32_16x16x64_i8(bfrag[0][1], a1_, ACC0, 0, 0, 0); \
        ACC1 = __builtin_amdgcn_mfma_i32_16x16x64_i8(bfrag[1][1], a1_, ACC1, 0, 0, 0); \
        ACC2 = __builtin_amdgcn_mfma_i32_16x16x64_i8(bfrag[2][1], a1_, ACC2, 0, 0, 0); \
        ACC3 = __builtin_amdgcn_mfma_i32_16x16x64_i8(bfrag[3][1], a1_, ACC3, 0, 0, 0); \
        ACC0 = __builtin_amdgcn_mfma_i32_16x16x64_i8(bfrag[0][2], a2_, ACC0, 0, 0, 0); \
        ACC1 = __builtin_amdgcn_mfma_i32_16x16x64_i8(bfrag[1][2], a2_, ACC1, 0, 0, 0); \
        ACC2 = __builtin_amdgcn_mfma_i32_16x16x64_i8(bfrag[2][2], a2_, ACC2, 0, 0, 0); \
        ACC3 = __builtin_amdgcn_mfma_i32_16x16x64_i8(bfrag[3][2], a2_, ACC3, 0, 0, 0); \
        ACC0 = __builtin_amdgcn_mfma_i32_16x16x64_i8(bfrag[0][3], a3_, ACC0, 0, 0, 0); \
        ACC1 = __builtin_amdgcn_mfma_i32_16x16x64_i8(bfrag[1][3], a3_, ACC1, 0, 0, 0); \
        ACC2 = __builtin_amdgcn_mfma_i32_16x16x64_i8(bfrag[2][3], a3_, ACC2, 0, 0, 0); \
        ACC3 = __builtin_amdgcn_mfma_i32_16x16x64_i8(bfrag[3][3], a3_, ACC3, 0, 0, 0); \
    } while (0)

    for (int t = 0; t < 95; ++t) {
        // prefetch step t+1's B-fragments
        const unsigned char* q = sp_base + (size_t)(t + 1) * 524288;
        uint4 nb0 = *(const uint4*)(q);
        uint4 nb1 = *(const uint4*)(q + 64);
        uint4 nb2 = *(const uint4*)(q + 128);
        uint4 nb3 = *(const uint4*)(q + 192);

        intx4 acc0 = {0,0,0,0}, acc1 = {0,0,0,0}, acc2 = {0,0,0,0}, acc3 = {0,0,0,0};
        STEP_MFMA(cb0, cb1, cb2, cb3, acc0, acc1, acc2, acc3);

        // exact fp32 limb combine + membrane update (reference fp32 op order)
        float4 sv;
#pragma unroll
        for (int r = 0; r < 4; ++r) {
            int a01 = acc0[r] * 128 + acc1[r];      // exact, |.| < 2^22
            int a23 = acc2[r] * 128 + acc3[r];
            float cur = fmaf((float)a01, 0x1p-13f, (float)a23 * 0x1p-27f)
                        + ((const float*)&biasv)[r];
            float vv = v[r];
            vv = vv + (cur - vv) * 0.5f;
            bool sp = (vv - 1.0f) >= 0.0f;
            v[r] = sp ? 0.0f : vv;                  // == vv*(1-s), s in {0,1}
            ((float*)&sv)[r] = sp ? 1.0f : 0.0f;
        }
        *(float4*)pb = sv;                          // full-line coalesced
        pb += 8192;
        cb0 = nb0; cb1 = nb1; cb2 = nb2; cb3 = nb3;
    }

    // --- peeled t = 95: same math + out1 stores ---
    {
        intx4 acc0 = {0,0,0,0}, acc1 = {0,0,0,0}, acc2 = {0,0,0,0}, acc3 = {0,0,0,0};
        STEP_MFMA(cb0, cb1, cb2, cb3, acc0, acc1, acc2, acc3);
        float4 sv;
#pragma unroll
        for (int r = 0; r < 4; ++r) {
            int a01 = acc0[r] * 128 + acc1[r];
            int a23 = acc2[r] * 128 + acc3[r];
            float cur = fmaf((float)a01, 0x1p-13f, (float)a23 * 0x1p-27f)
                        + ((const float*)&biasv)[r];
            float vv = v[r];
            vv = vv + (cur - vv) * 0.5f;
            bool sp = (vv - 1.0f) >= 0.0f;
            ((float*)&sv)[r] = sp ? 1.0f : 0.0f;
        }
        *(float4*)pb = sv;
        *(float4*)(out1 + (size_t)(nw + m) * 256 + o0 + g * 4) = sv;
    }
    #undef STEP_MFMA
}

// ---------------------------------------------------------------------------
extern "C" void kernel_launch(void* const* d_in, const int* in_sizes, int n_in,
                              void* d_out, int out_size, void* d_ws, size_t ws_size,
                              hipStream_t stream) {
    const float* inputs = (const float*)d_in[0];   // [64,96,32]
    const float* w_enc  = (const float*)d_in[1];   // [256,1,3]
    const float* b_enc  = (const float*)d_in[2];   // [256]
    const float* w_rnn  = (const float*)d_in[3];   // [2,256,256]
    const float* b_rnn  = (const float*)d_in[4];   // [2,256]

    float* out0 = (float*)d_out;                       // [64,96,8192]
    float* out1 = out0 + (size_t)64 * 96 * 8192;       // [64,8192]

    char* ws = (char*)d_ws;
    double*        Wd  = (double*)(ws);                //  768 doubles  [0,6144)
    double*        C0d = (double*)(ws + 6144);         //  256 doubles  [6144,8192)
    signed char*   Bw8 = (signed char*)(ws + 8192);    //  256*4*256 i8 [8192,270336)
    unsigned char* s0B = (unsigned char*)(ws + 270336);// 96*524288 B spike bytes (50MB)

    prep_kernel<<<256, 64, 0, stream>>>(w_enc, b_enc, w_rnn, b_rnn, Wd, C0d, Bw8);
    enc_kernel<<<2048, 256, 0, stream>>>(inputs, Wd, C0d, s0B);
    rnn_kernel<<<512, 256, 0, stream>>>(s0B, Bw8, b_rnn, out0, out1);
}

// Round 12
// 273.637 us; speedup vs baseline: 1.2231x; 1.0861x over previous
//
#include <hip/hip_runtime.h>
#include <hip/hip_bf16.h>
#include <stdint.h>

// Problem constants: B=64, L=96, C=32, H=256, NL=2, K=3, TAU=2, VTH=1
// n = b*32 + c indexes the B*C=2048 "rows"; layer width H=256.

using floatx4 = __attribute__((ext_vector_type(4))) float;
using intx4   = __attribute__((ext_vector_type(4))) int;

// ---------------------------------------------------------------------------
// prep: per output-neuron o (256 blocks x 64 threads)
//  - W[o][k]  = sum_i w0[o,i]*w_enc[i,k]   (fp64)
//  - C0[o]    = sum_i b_enc[i]*w0[o,i] + b_rnn[0][o]  (fp64)
//  - i8 4-limb digit planes of w1: q=rn(w*2^27), q=((d0*128+d1)*128+d2)*128+d3,
//    digits in [-64,63]. Bw8[o][l][k] = d_l of w1[o][k]. EXACT (|w|<1).
// ---------------------------------------------------------------------------
__global__ void prep_kernel(const float* __restrict__ w_enc,
                            const float* __restrict__ b_enc,
                            const float* __restrict__ w_rnn,
                            const float* __restrict__ b_rnn,
                            double* __restrict__ Wd,
                            double* __restrict__ C0d,
                            signed char* __restrict__ Bw8)
{
    const int o = blockIdx.x;
    const int lane = threadIdx.x;   // 64 threads
    const float4 w0v = *(const float4*)(w_rnn + (size_t)o * 256 + lane * 4);
    double a0 = 0.0, a1 = 0.0, a2 = 0.0, ab = 0.0;
#pragma unroll
    for (int e = 0; e < 4; ++e) {
        const int i = lane * 4 + e;
        const double wv = (double)(((const float*)&w0v)[e]);
        a0 += wv * (double)w_enc[i * 3 + 0];
        a1 += wv * (double)w_enc[i * 3 + 1];
        a2 += wv * (double)w_enc[i * 3 + 2];
        ab += wv * (double)b_enc[i];
    }
    for (int off = 32; off > 0; off >>= 1) {
        a0 += __shfl_down(a0, off, 64);
        a1 += __shfl_down(a1, off, 64);
        a2 += __shfl_down(a2, off, 64);
        ab += __shfl_down(ab, off, 64);
    }
    if (lane == 0) {
        Wd[o * 3 + 0] = a0;
        Wd[o * 3 + 1] = a1;
        Wd[o * 3 + 2] = a2;
        C0d[o] = ab + (double)b_rnn[o];
    }
    // i8 digit planes of w1 (layer-1), 4 consecutive k per lane
    const float4 w1v = *(const float4*)(w_rnn + 65536 + (size_t)o * 256 + lane * 4);
    unsigned int pack[4] = {0u, 0u, 0u, 0u};   // pack[l]: digits for e=0..3
#pragma unroll
    for (int e = 0; e < 4; ++e) {
        float f = ((const float*)&w1v)[e];
        int q = __double2int_rn((double)f * 134217728.0);   // w * 2^27, |q| <= 2^27
        int d3 = ((q + 64) & 127) - 64;  q = (q - d3) >> 7;
        int d2 = ((q + 64) & 127) - 64;  q = (q - d2) >> 7;
        int d1 = ((q + 64) & 127) - 64;  q = (q - d1) >> 7;
        int d0 = q;                       // |d0| <= 64
        pack[0] |= ((unsigned int)(d0 & 0xFF)) << (8 * e);
        pack[1] |= ((unsigned int)(d1 & 0xFF)) << (8 * e);
        pack[2] |= ((unsigned int)(d2 & 0xFF)) << (8 * e);
        pack[3] |= ((unsigned int)(d3 & 0xFF)) << (8 * e);
    }
#pragma unroll
    for (int l = 0; l < 4; ++l)
        *(unsigned int*)(Bw8 + ((size_t)o * 4 + l) * 256 + lane * 4) = pack[l];
}

// ---------------------------------------------------------------------------
// enc: layer-0 full scan. 2048 blocks x 256 threads. cur0 in fp64 (correctly
// rounded), membrane chain in exact reference fp32 op order. Spike mask rows
// stored HALFWORD-TRANSPOSED: row (t,n) is 32B; global halfword h=i/16
// (h = 4*wave + j) lands at byte offset 8*j + 2*wave -> rnn lane (g,m) reads
// one aligned uint2 at +8g = exactly the k-bits its 4 MFMA chunks need.
// ---------------------------------------------------------------------------
__global__ void enc_kernel(const float* __restrict__ inputs,
                           const double* __restrict__ Wd,
                           const double* __restrict__ C0d,
                           unsigned char* __restrict__ s0b)
{
    const int n = blockIdx.x;
    const int tidx = threadIdx.x;
    const int b = n >> 5, c = n & 31;
    __shared__ float xr[98];
    if (tidx < 96)       xr[tidx + 1] = inputs[((size_t)b * 96 + tidx) * 32 + c];
    else if (tidx == 96) xr[0]  = 0.0f;
    else if (tidx == 97) xr[97] = 0.0f;
    __syncthreads();
    const double W0 = Wd[tidx * 3], W1 = Wd[tidx * 3 + 1], W2 = Wd[tidx * 3 + 2];
    const double c0 = C0d[tidx];
    const int wid = tidx >> 6, lane = tidx & 63;
    float v = 0.0f;
    for (int t = 0; t < 96; ++t) {
        float cur = (float)((double)xr[t] * W0 + (double)xr[t + 1] * W1 +
                            (double)xr[t + 2] * W2 + c0);
        float vv = v + (cur - v) * 0.5f;
        int sp = (vv - 1.0f) >= 0.0f;
        v = sp ? 0.0f : vv;
        unsigned long long bal = __ballot(sp);
        if ((lane & 15) == 0) {
            const int j = lane >> 4;
            *(unsigned short*)(s0b + ((size_t)t * 2048 + n) * 32 + 8 * j + 2 * wid)
                = (unsigned short)(bal >> (16 * j));
        }
    }
}

// ---------------------------------------------------------------------------
// rnn: layer-1, i8 4-limb exact MFMA, NO LDS, NO barriers (R8 structure).
// 2048 wave-jobs (512 blocks x 4 waves); wave = 16 rows x 16 cols; the 4
// waves of a block share the same 16 rows (L1 mask reuse).
// R11/R12 change: out0/out1 stores are NONTEMPORAL (nt streaming hint),
// via ext_vector_type floatx4 (HIP float4 struct is rejected by the
// builtin). Theory: plain stores land in L2 as scattered dirty lines and
// write back in set/way order, destroying DRAM page locality (observed
// 3.2 TB/s vs 6.5 for the sequential fill); nt streams them out in issue
// order.
// Decision math BIT-IDENTICAL to R8: i8 limb MFMA (exact), fp32 limb combine
// fmaf((float)a01, 2^-13, (float)a23*2^-27) == RN(exact sum); membrane in
// exact reference fp32 op order; sp?0:vv == vv*(1-s) for s in {0,1}.
// ---------------------------------------------------------------------------
__global__ __launch_bounds__(256, 2) void rnn_kernel(
    const unsigned char* __restrict__ s0b,
    const signed char* __restrict__ Bw8,
    const float* __restrict__ b_rnn,
    float* __restrict__ out0,
    float* __restrict__ out1)
{
    const int tid  = threadIdx.x;
    const int wid  = tid >> 6, lane = tid & 63;
    const int m    = lane & 15, g = lane >> 4;
    const int job  = blockIdx.x * 4 + wid;          // 2048 jobs
    const int rt   = job >> 4;                      // 128 row-tiles
    const int nw   = rt * 16;
    const int o0   = (job & 15) * 16;               // 16 col-tiles

    // --- weight A-fragments (loop-invariant): 4 limbs x 4 chunks = 64 VGPRs
    intx4 bfrag[4][4];
#pragma unroll
    for (int l = 0; l < 4; ++l)
#pragma unroll
        for (int c = 0; c < 4; ++c)
            bfrag[l][c] = *(const intx4*)(Bw8 + ((size_t)(o0 + m) * 4 + l) * 256
                                               + c * 64 + g * 16);
    // per-lane bias for out-cols o0+4g .. o0+4g+3
    const float4 biasv = *(const float4*)(b_rnn + 256 + o0 + g * 4);

    // --- store base: spike-row nw+m, col o0+4g (16B-aligned) ---
    float* pb = out0 + ((size_t)(nw >> 5) * 96) * 8192
                     + (size_t)((nw & 31) + m) * 256 + o0 + g * 4;

    // --- mask stream: lane reads uint2 at row*32 + 8g, prefetched 2 ahead ---
    const unsigned char* mp = s0b + ((size_t)(nw + m)) * 32 + 8 * g;
    uint2 m0 = *(const uint2*)(mp);
    uint2 m1 = *(const uint2*)(mp + 65536);

    floatx4 v = {0.f, 0.f, 0.f, 0.f};

    #define STEP_MFMA(MASK, ACC0, ACC1, ACC2, ACC3)                            \
    do {                                                                       \
        unsigned int hw_[4] = { (MASK).x & 0xFFFFu, (MASK).x >> 16,            \
                                (MASK).y & 0xFFFFu, (MASK).y >> 16 };          \
        _Pragma("unroll")                                                      \
        for (int c = 0; c < 4; ++c) {                                          \
            unsigned int h_ = hw_[c];                                          \
            intx4 a_;                                                          \
            a_.x = (int)((( h_        & 0xFu) * 0x00204081u) & 0x01010101u);   \
            a_.y = (int)((((h_ >> 4)  & 0xFu) * 0x00204081u) & 0x01010101u);   \
            a_.z = (int)((((h_ >> 8)  & 0xFu) * 0x00204081u) & 0x01010101u);   \
            a_.w = (int)((((h_ >> 12) & 0xFu) * 0x00204081u) & 0x01010101u);   \
            ACC0 = __builtin_amdgcn_mfma_i32_16x16x64_i8(bfrag[0][c], a_, ACC0, 0, 0, 0); \
            ACC1 = __builtin_amdgcn_mfma_i32_16x16x64_i8(bfrag[1][c], a_, ACC1, 0, 0, 0); \
            ACC2 = __builtin_amdgcn_mfma_i32_16x16x64_i8(bfrag[2][c], a_, ACC2, 0, 0, 0); \
            ACC3 = __builtin_amdgcn_mfma_i32_16x16x64_i8(bfrag[3][c], a_, ACC3, 0, 0, 0); \
        }                                                                      \
    } while (0)

    for (int t = 0; t < 95; ++t) {
        uint2 nxt = m1;
        m1 = *(const uint2*)(mp + (size_t)(t + 2) * 65536);   // slots 96/97 padded

        intx4 acc0 = {0,0,0,0}, acc1 = {0,0,0,0}, acc2 = {0,0,0,0}, acc3 = {0,0,0,0};
        STEP_MFMA(m0, acc0, acc1, acc2, acc3);

        // exact fp32 limb combine + membrane update (reference fp32 op order)
        floatx4 sv;
#pragma unroll
        for (int r = 0; r < 4; ++r) {
            int a01 = acc0[r] * 128 + acc1[r];      // exact, |.| < 2^22
            int a23 = acc2[r] * 128 + acc3[r];
            float cur = fmaf((float)a01, 0x1p-13f, (float)a23 * 0x1p-27f)
                        + ((const float*)&biasv)[r];
            float vv = v[r];
            vv = vv + (cur - vv) * 0.5f;
            float s = ((vv - 1.0f) >= 0.0f) ? 1.0f : 0.0f;
            v[r] = vv * (1.0f - s);
            sv[r] = s;
        }
        __builtin_nontemporal_store(sv, (floatx4*)pb);   // nt streaming store
        pb += 8192;
        m0 = nxt;
    }

    // --- peeled t = 95: same math + out1 stores ---
    {
        intx4 acc0 = {0,0,0,0}, acc1 = {0,0,0,0}, acc2 = {0,0,0,0}, acc3 = {0,0,0,0};
        STEP_MFMA(m0, acc0, acc1, acc2, acc3);
        floatx4 sv;
#pragma unroll
        for (int r = 0; r < 4; ++r) {
            int a01 = acc0[r] * 128 + acc1[r];
            int a23 = acc2[r] * 128 + acc3[r];
            float cur = fmaf((float)a01, 0x1p-13f, (float)a23 * 0x1p-27f)
                        + ((const float*)&biasv)[r];
            float vv = v[r];
            vv = vv + (cur - vv) * 0.5f;
            float s = ((vv - 1.0f) >= 0.0f) ? 1.0f : 0.0f;
            sv[r] = s;
        }
        __builtin_nontemporal_store(sv, (floatx4*)pb);
        __builtin_nontemporal_store(sv,
            (floatx4*)(out1 + (size_t)(nw + m) * 256 + o0 + g * 4));
    }
    #undef STEP_MFMA
}

// ---------------------------------------------------------------------------
extern "C" void kernel_launch(void* const* d_in, const int* in_sizes, int n_in,
                              void* d_out, int out_size, void* d_ws, size_t ws_size,
                              hipStream_t stream) {
    const float* inputs = (const float*)d_in[0];   // [64,96,32]
    const float* w_enc  = (const float*)d_in[1];   // [256,1,3]
    const float* b_enc  = (const float*)d_in[2];   // [256]
    const float* w_rnn  = (const float*)d_in[3];   // [2,256,256]
    const float* b_rnn  = (const float*)d_in[4];   // [2,256]

    float* out0 = (float*)d_out;                       // [64,96,8192]
    float* out1 = out0 + (size_t)64 * 96 * 8192;       // [64,8192]

    char* ws = (char*)d_ws;
    double*      Wd  = (double*)(ws);                  //  768 doubles  [0,6144)
    double*      C0d = (double*)(ws + 6144);           //  256 doubles  [6144,8192)
    signed char* Bw8 = (signed char*)(ws + 8192);      //  256*4*256 i8 [8192,270336)
    unsigned char* s0b = (unsigned char*)(ws + 270336);// 98*65536 B spike bits (2 pad slots)

    prep_kernel<<<256, 64, 0, stream>>>(w_enc, b_enc, w_rnn, b_rnn, Wd, C0d, Bw8);
    enc_kernel<<<2048, 256, 0, stream>>>(inputs, Wd, C0d, s0b);
    rnn_kernel<<<512, 256, 0, stream>>>(s0b, Bw8, b_rnn, out0, out1);
}

// Round 13
// 254.319 us; speedup vs baseline: 1.3160x; 1.0760x over previous
//
#include <hip/hip_runtime.h>
#include <hip/hip_bf16.h>
#include <stdint.h>

// Problem constants: B=64, L=96, C=32, H=256, NL=2, K=3, TAU=2, VTH=1
// n = b*32 + c indexes the B*C=2048 "rows"; layer width H=256.

using floatx4 = __attribute__((ext_vector_type(4))) float;
using intx4   = __attribute__((ext_vector_type(4))) int;

// ---------------------------------------------------------------------------
// prep: per output-neuron o (256 blocks x 64 threads)
//  - W[o][k]  = sum_i w0[o,i]*w_enc[i,k]   (fp64)
//  - C0[o]    = sum_i b_enc[i]*w0[o,i] + b_rnn[0][o]  (fp64)
//  - i8 4-limb digit planes of w1: q=rn(w*2^27), q=((d0*128+d1)*128+d2)*128+d3,
//    digits in [-64,63]. Bw8[o][l][k] = d_l of w1[o][k].
// ---------------------------------------------------------------------------
__global__ void prep_kernel(const float* __restrict__ w_enc,
                            const float* __restrict__ b_enc,
                            const float* __restrict__ w_rnn,
                            const float* __restrict__ b_rnn,
                            double* __restrict__ Wd,
                            double* __restrict__ C0d,
                            signed char* __restrict__ Bw8)
{
    const int o = blockIdx.x;
    const int lane = threadIdx.x;   // 64 threads
    const float4 w0v = *(const float4*)(w_rnn + (size_t)o * 256 + lane * 4);
    double a0 = 0.0, a1 = 0.0, a2 = 0.0, ab = 0.0;
#pragma unroll
    for (int e = 0; e < 4; ++e) {
        const int i = lane * 4 + e;
        const double wv = (double)(((const float*)&w0v)[e]);
        a0 += wv * (double)w_enc[i * 3 + 0];
        a1 += wv * (double)w_enc[i * 3 + 1];
        a2 += wv * (double)w_enc[i * 3 + 2];
        ab += wv * (double)b_enc[i];
    }
    for (int off = 32; off > 0; off >>= 1) {
        a0 += __shfl_down(a0, off, 64);
        a1 += __shfl_down(a1, off, 64);
        a2 += __shfl_down(a2, off, 64);
        ab += __shfl_down(ab, off, 64);
    }
    if (lane == 0) {
        Wd[o * 3 + 0] = a0;
        Wd[o * 3 + 1] = a1;
        Wd[o * 3 + 2] = a2;
        C0d[o] = ab + (double)b_rnn[o];
    }
    // i8 digit planes of w1 (layer-1), 4 consecutive k per lane
    const float4 w1v = *(const float4*)(w_rnn + 65536 + (size_t)o * 256 + lane * 4);
    unsigned int pack[4] = {0u, 0u, 0u, 0u};   // pack[l]: digits for e=0..3
#pragma unroll
    for (int e = 0; e < 4; ++e) {
        float f = ((const float*)&w1v)[e];
        int q = __double2int_rn((double)f * 134217728.0);   // w * 2^27, |q| <= 2^27
        int d3 = ((q + 64) & 127) - 64;  q = (q - d3) >> 7;
        int d2 = ((q + 64) & 127) - 64;  q = (q - d2) >> 7;
        int d1 = ((q + 64) & 127) - 64;  q = (q - d1) >> 7;
        int d0 = q;                       // |d0| <= 64
        pack[0] |= ((unsigned int)(d0 & 0xFF)) << (8 * e);
        pack[1] |= ((unsigned int)(d1 & 0xFF)) << (8 * e);
        pack[2] |= ((unsigned int)(d2 & 0xFF)) << (8 * e);
        pack[3] |= ((unsigned int)(d3 & 0xFF)) << (8 * e);
    }
#pragma unroll
    for (int l = 0; l < 4; ++l)
        *(unsigned int*)(Bw8 + ((size_t)o * 4 + l) * 256 + lane * 4) = pack[l];
}

// ---------------------------------------------------------------------------
// enc: layer-0 full scan. 2048 blocks x 256 threads. cur0 in fp64 (correctly
// rounded), membrane chain in exact reference fp32 op order. Spike mask rows
// stored HALFWORD-TRANSPOSED: row (t,n) is 32B; global halfword h=i/16
// (h = 4*wave + j) lands at byte offset 8*j + 2*wave -> rnn lane (g,m) reads
// one aligned uint2 at +8g = exactly the k-bits its 4 MFMA chunks need.
// ---------------------------------------------------------------------------
__global__ void enc_kernel(const float* __restrict__ inputs,
                           const double* __restrict__ Wd,
                           const double* __restrict__ C0d,
                           unsigned char* __restrict__ s0b)
{
    const int n = blockIdx.x;
    const int tidx = threadIdx.x;
    const int b = n >> 5, c = n & 31;
    __shared__ float xr[98];
    if (tidx < 96)       xr[tidx + 1] = inputs[((size_t)b * 96 + tidx) * 32 + c];
    else if (tidx == 96) xr[0]  = 0.0f;
    else if (tidx == 97) xr[97] = 0.0f;
    __syncthreads();
    const double W0 = Wd[tidx * 3], W1 = Wd[tidx * 3 + 1], W2 = Wd[tidx * 3 + 2];
    const double c0 = C0d[tidx];
    const int wid = tidx >> 6, lane = tidx & 63;
    float v = 0.0f;
    for (int t = 0; t < 96; ++t) {
        float cur = (float)((double)xr[t] * W0 + (double)xr[t + 1] * W1 +
                            (double)xr[t + 2] * W2 + c0);
        float vv = v + (cur - v) * 0.5f;
        int sp = (vv - 1.0f) >= 0.0f;
        v = sp ? 0.0f : vv;
        unsigned long long bal = __ballot(sp);
        if ((lane & 15) == 0) {
            const int j = lane >> 4;
            *(unsigned short*)(s0b + ((size_t)t * 2048 + n) * 32 + 8 * j + 2 * wid)
                = (unsigned short)(bal >> (16 * j));
        }
    }
}

// ---------------------------------------------------------------------------
// rnn: layer-1, i8 4-limb exact MFMA, NO LDS, NO barriers.
// R13: 2-deep software pipeline. 1024 blocks x 2 waves (128 thr,
// __launch_bounds__(128,2) -> 256-VGPR budget, 4 blocks/CU = 8 waves/CU
// unchanged). Each iteration computes MFMAs for steps t AND t+1 with
// INDEPENDENT accumulator sets, so step t+1's matrix work (depends only on
// prefetched masks, not on v) overlaps step t's membrane VALU + store drain.
// Decision math BIT-IDENTICAL to R8 per step: i8 limb MFMA (exact), fp32
// limb combine fmaf((float)a01, 2^-13, (float)a23*2^-27) == RN(exact sum);
// membrane in exact reference fp32 op order; vv*(1-s) hard reset.
// C/D 16x16: M=(lane>>4)*4+reg -> out-col; N=lane&15 -> spike-row.
// ---------------------------------------------------------------------------
__global__ __launch_bounds__(128, 2) void rnn_kernel(
    const unsigned char* __restrict__ s0b,
    const signed char* __restrict__ Bw8,
    const float* __restrict__ b_rnn,
    float* __restrict__ out0,
    float* __restrict__ out1)
{
    const int tid  = threadIdx.x;
    const int wid  = tid >> 6, lane = tid & 63;
    const int m    = lane & 15, g = lane >> 4;
    const int job  = blockIdx.x * 2 + wid;          // 2048 jobs
    const int rt   = job >> 4;                      // 128 row-tiles
    const int nw   = rt * 16;
    const int o0   = (job & 15) * 16;               // 16 col-tiles

    // --- weight A-fragments (loop-invariant): 4 limbs x 4 chunks = 64 VGPRs
    intx4 bfrag[4][4];
#pragma unroll
    for (int l = 0; l < 4; ++l)
#pragma unroll
        for (int c = 0; c < 4; ++c)
            bfrag[l][c] = *(const intx4*)(Bw8 + ((size_t)(o0 + m) * 4 + l) * 256
                                               + c * 64 + g * 16);
    // per-lane bias for out-cols o0+4g .. o0+4g+3
    const float4 biasv = *(const float4*)(b_rnn + 256 + o0 + g * 4);

    // --- store base: spike-row nw+m, col o0+4g (16B-aligned) ---
    float* pb = out0 + ((size_t)(nw >> 5) * 96) * 8192
                     + (size_t)((nw & 31) + m) * 256 + o0 + g * 4;

    // --- mask stream: lane reads uint2 at row*32 + 8g, 2 steps in hand ---
    const unsigned char* mp = s0b + ((size_t)(nw + m)) * 32 + 8 * g;
    uint2 m0 = *(const uint2*)(mp);
    uint2 m1 = *(const uint2*)(mp + 65536);

    floatx4 v = {0.f, 0.f, 0.f, 0.f};

    #define STEP_MFMA(MASK, ACC0, ACC1, ACC2, ACC3)                            \
    do {                                                                       \
        unsigned int hw_[4] = { (MASK).x & 0xFFFFu, (MASK).x >> 16,            \
                                (MASK).y & 0xFFFFu, (MASK).y >> 16 };          \
        _Pragma("unroll")                                                      \
        for (int c = 0; c < 4; ++c) {                                          \
            unsigned int h_ = hw_[c];                                          \
            intx4 a_;                                                          \
            a_.x = (int)((( h_        & 0xFu) * 0x00204081u) & 0x01010101u);   \
            a_.y = (int)((((h_ >> 4)  & 0xFu) * 0x00204081u) & 0x01010101u);   \
            a_.z = (int)((((h_ >> 8)  & 0xFu) * 0x00204081u) & 0x01010101u);   \
            a_.w = (int)((((h_ >> 12) & 0xFu) * 0x00204081u) & 0x01010101u);   \
            ACC0 = __builtin_amdgcn_mfma_i32_16x16x64_i8(bfrag[0][c], a_, ACC0, 0, 0, 0); \
            ACC1 = __builtin_amdgcn_mfma_i32_16x16x64_i8(bfrag[1][c], a_, ACC1, 0, 0, 0); \
            ACC2 = __builtin_amdgcn_mfma_i32_16x16x64_i8(bfrag[2][c], a_, ACC2, 0, 0, 0); \
            ACC3 = __builtin_amdgcn_mfma_i32_16x16x64_i8(bfrag[3][c], a_, ACC3, 0, 0, 0); \
        }                                                                      \
    } while (0)

    #define MEMBRANE(ACC0, ACC1, ACC2, ACC3, SV)                               \
    do {                                                                       \
        _Pragma("unroll")                                                      \
        for (int r = 0; r < 4; ++r) {                                          \
            int a01 = (ACC0)[r] * 128 + (ACC1)[r];   /* exact, |.| < 2^22 */   \
            int a23 = (ACC2)[r] * 128 + (ACC3)[r];                             \
            float cur = fmaf((float)a01, 0x1p-13f, (float)a23 * 0x1p-27f)      \
                        + ((const float*)&biasv)[r];                           \
            float vv = v[r];                                                   \
            vv = vv + (cur - vv) * 0.5f;                                       \
            float s = ((vv - 1.0f) >= 0.0f) ? 1.0f : 0.0f;                     \
            v[r] = vv * (1.0f - s);                                            \
            (SV)[r] = s;                                                       \
        }                                                                      \
    } while (0)

    // pairs (0,1)..(92,93); peeled (94,95)
    for (int t = 0; t < 94; t += 2) {
        uint2 p2 = *(const uint2*)(mp + (size_t)(t + 2) * 65536);
        uint2 p3 = *(const uint2*)(mp + (size_t)(t + 3) * 65536);

        intx4 aa0 = {0,0,0,0}, aa1 = {0,0,0,0}, aa2 = {0,0,0,0}, aa3 = {0,0,0,0};
        intx4 ba0 = {0,0,0,0}, ba1 = {0,0,0,0}, ba2 = {0,0,0,0}, ba3 = {0,0,0,0};
        STEP_MFMA(m0, aa0, aa1, aa2, aa3);   // step t
        STEP_MFMA(m1, ba0, ba1, ba2, ba3);   // step t+1 (independent accs)

        floatx4 sva, svb;
        MEMBRANE(aa0, aa1, aa2, aa3, sva);
        *(floatx4*)pb = sva;
        MEMBRANE(ba0, ba1, ba2, ba3, svb);
        *(floatx4*)(pb + 8192) = svb;

        pb += 16384;
        m0 = p2; m1 = p3;
    }

    // --- peeled pair t = 94, 95 (masks already in m0, m1) ---
    {
        intx4 aa0 = {0,0,0,0}, aa1 = {0,0,0,0}, aa2 = {0,0,0,0}, aa3 = {0,0,0,0};
        intx4 ba0 = {0,0,0,0}, ba1 = {0,0,0,0}, ba2 = {0,0,0,0}, ba3 = {0,0,0,0};
        STEP_MFMA(m0, aa0, aa1, aa2, aa3);
        STEP_MFMA(m1, ba0, ba1, ba2, ba3);
        floatx4 sva, svb;
        MEMBRANE(aa0, aa1, aa2, aa3, sva);
        *(floatx4*)pb = sva;
        MEMBRANE(ba0, ba1, ba2, ba3, svb);
        *(floatx4*)(pb + 8192) = svb;
        *(floatx4*)(out1 + (size_t)(nw + m) * 256 + o0 + g * 4) = svb;
    }
    #undef STEP_MFMA
    #undef MEMBRANE
}

// ---------------------------------------------------------------------------
extern "C" void kernel_launch(void* const* d_in, const int* in_sizes, int n_in,
                              void* d_out, int out_size, void* d_ws, size_t ws_size,
                              hipStream_t stream) {
    const float* inputs = (const float*)d_in[0];   // [64,96,32]
    const float* w_enc  = (const float*)d_in[1];   // [256,1,3]
    const float* b_enc  = (const float*)d_in[2];   // [256]
    const float* w_rnn  = (const float*)d_in[3];   // [2,256,256]
    const float* b_rnn  = (const float*)d_in[4];   // [2,256]

    float* out0 = (float*)d_out;                       // [64,96,8192]
    float* out1 = out0 + (size_t)64 * 96 * 8192;       // [64,8192]

    char* ws = (char*)d_ws;
    double*      Wd  = (double*)(ws);                  //  768 doubles  [0,6144)
    double*      C0d = (double*)(ws + 6144);           //  256 doubles  [6144,8192)
    signed char* Bw8 = (signed char*)(ws + 8192);      //  256*4*256 i8 [8192,270336)
    unsigned char* s0b = (unsigned char*)(ws + 270336);// 98*65536 B spike bits (2 pad slots)

    prep_kernel<<<256, 64, 0, stream>>>(w_enc, b_enc, w_rnn, b_rnn, Wd, C0d, Bw8);
    enc_kernel<<<2048, 256, 0, stream>>>(inputs, Wd, C0d, s0b);
    rnn_kernel<<<1024, 128, 0, stream>>>(s0b, Bw8, b_rnn, out0, out1);
}

// Round 14
// 251.976 us; speedup vs baseline: 1.3282x; 1.0093x over previous
//
#include <hip/hip_runtime.h>
#include <hip/hip_bf16.h>
#include <stdint.h>

// Problem constants: B=64, L=96, C=32, H=256, NL=2, K=3, TAU=2, VTH=1
// n = b*32 + c indexes the B*C=2048 "rows"; layer width H=256.

using floatx4 = __attribute__((ext_vector_type(4))) float;
using intx4   = __attribute__((ext_vector_type(4))) int;

// ---------------------------------------------------------------------------
// prep: per output-neuron o (256 blocks x 64 threads)
//  - W[o][k]  = sum_i w0[o,i]*w_enc[i,k]   (fp64)
//  - C0[o]    = sum_i b_enc[i]*w0[o,i] + b_rnn[0][o]  (fp64)
//  - i8 4-limb digit planes of w1: q=rn(w*2^27), q=((d0*128+d1)*128+d2)*128+d3,
//    digits in [-64,63]. Bw8[o][l][k] = d_l of w1[o][k].
// ---------------------------------------------------------------------------
__global__ void prep_kernel(const float* __restrict__ w_enc,
                            const float* __restrict__ b_enc,
                            const float* __restrict__ w_rnn,
                            const float* __restrict__ b_rnn,
                            double* __restrict__ Wd,
                            double* __restrict__ C0d,
                            signed char* __restrict__ Bw8)
{
    const int o = blockIdx.x;
    const int lane = threadIdx.x;   // 64 threads
    const float4 w0v = *(const float4*)(w_rnn + (size_t)o * 256 + lane * 4);
    double a0 = 0.0, a1 = 0.0, a2 = 0.0, ab = 0.0;
#pragma unroll
    for (int e = 0; e < 4; ++e) {
        const int i = lane * 4 + e;
        const double wv = (double)(((const float*)&w0v)[e]);
        a0 += wv * (double)w_enc[i * 3 + 0];
        a1 += wv * (double)w_enc[i * 3 + 1];
        a2 += wv * (double)w_enc[i * 3 + 2];
        ab += wv * (double)b_enc[i];
    }
    for (int off = 32; off > 0; off >>= 1) {
        a0 += __shfl_down(a0, off, 64);
        a1 += __shfl_down(a1, off, 64);
        a2 += __shfl_down(a2, off, 64);
        ab += __shfl_down(ab, off, 64);
    }
    if (lane == 0) {
        Wd[o * 3 + 0] = a0;
        Wd[o * 3 + 1] = a1;
        Wd[o * 3 + 2] = a2;
        C0d[o] = ab + (double)b_rnn[o];
    }
    // i8 digit planes of w1 (layer-1), 4 consecutive k per lane
    const float4 w1v = *(const float4*)(w_rnn + 65536 + (size_t)o * 256 + lane * 4);
    unsigned int pack[4] = {0u, 0u, 0u, 0u};   // pack[l]: digits for e=0..3
#pragma unroll
    for (int e = 0; e < 4; ++e) {
        float f = ((const float*)&w1v)[e];
        int q = __double2int_rn((double)f * 134217728.0);   // w * 2^27, |q| <= 2^27
        int d3 = ((q + 64) & 127) - 64;  q = (q - d3) >> 7;
        int d2 = ((q + 64) & 127) - 64;  q = (q - d2) >> 7;
        int d1 = ((q + 64) & 127) - 64;  q = (q - d1) >> 7;
        int d0 = q;                       // |d0| <= 64
        pack[0] |= ((unsigned int)(d0 & 0xFF)) << (8 * e);
        pack[1] |= ((unsigned int)(d1 & 0xFF)) << (8 * e);
        pack[2] |= ((unsigned int)(d2 & 0xFF)) << (8 * e);
        pack[3] |= ((unsigned int)(d3 & 0xFF)) << (8 * e);
    }
#pragma unroll
    for (int l = 0; l < 4; ++l)
        *(unsigned int*)(Bw8 + ((size_t)o * 4 + l) * 256 + lane * 4) = pack[l];
}

// ---------------------------------------------------------------------------
// enc: layer-0 full scan. 2048 blocks x 256 threads. cur0 in fp64 (correctly
// rounded), membrane chain in exact reference fp32 op order. Spike mask rows
// stored HALFWORD-TRANSPOSED: row (t,n) is 32B; global halfword h=i/16
// (h = 4*wave + j) lands at byte offset 8*j + 2*wave -> rnn lane (g,m) reads
// one aligned uint2 at +8g = exactly the k-bits its 4 MFMA chunks need.
// ---------------------------------------------------------------------------
__global__ void enc_kernel(const float* __restrict__ inputs,
                           const double* __restrict__ Wd,
                           const double* __restrict__ C0d,
                           unsigned char* __restrict__ s0b)
{
    const int n = blockIdx.x;
    const int tidx = threadIdx.x;
    const int b = n >> 5, c = n & 31;
    __shared__ float xr[98];
    if (tidx < 96)       xr[tidx + 1] = inputs[((size_t)b * 96 + tidx) * 32 + c];
    else if (tidx == 96) xr[0]  = 0.0f;
    else if (tidx == 97) xr[97] = 0.0f;
    __syncthreads();
    const double W0 = Wd[tidx * 3], W1 = Wd[tidx * 3 + 1], W2 = Wd[tidx * 3 + 2];
    const double c0 = C0d[tidx];
    const int wid = tidx >> 6, lane = tidx & 63;
    float v = 0.0f;
    for (int t = 0; t < 96; ++t) {
        float cur = (float)((double)xr[t] * W0 + (double)xr[t + 1] * W1 +
                            (double)xr[t + 2] * W2 + c0);
        float vv = v + (cur - v) * 0.5f;
        int sp = (vv - 1.0f) >= 0.0f;
        v = sp ? 0.0f : vv;
        unsigned long long bal = __ballot(sp);
        if ((lane & 15) == 0) {
            const int j = lane >> 4;
            *(unsigned short*)(s0b + ((size_t)t * 2048 + n) * 32 + 8 * j + 2 * wid)
                = (unsigned short)(bal >> (16 * j));
        }
    }
}

// ---------------------------------------------------------------------------
// rnn: layer-1, i8 4-limb exact MFMA, NO LDS, NO barriers.
// R14: 3-deep software pipeline (R13 was 2-deep). 1024 blocks x 2 waves
// (128 thr, __launch_bounds__(128,2) -> 256-VGPR budget, 4 blocks/CU =
// 8 waves/CU). Each iteration computes MFMAs for steps t, t+1, t+2 with
// INDEPENDENT accumulator sets (12 independent 4-MFMA chains live), so the
// matrix work of later steps (depends only on prefetched masks, not on v)
// overlaps earlier steps' membrane VALU + store drain. Bit-spread muls use
// __umul24 (operands < 2^24) -> full-rate v_mul_u32_u24.
// Decision math BIT-IDENTICAL to R8/R13 per step: i8 limb MFMA (exact), fp32
// limb combine fmaf((float)a01, 2^-13, (float)a23*2^-27) == RN(exact sum);
// membrane in exact reference fp32 op order; vv*(1-s) hard reset.
// C/D 16x16: M=(lane>>4)*4+reg -> out-col; N=lane&15 -> spike-row.
// ---------------------------------------------------------------------------
__global__ __launch_bounds__(128, 2) void rnn_kernel(
    const unsigned char* __restrict__ s0b,
    const signed char* __restrict__ Bw8,
    const float* __restrict__ b_rnn,
    float* __restrict__ out0,
    float* __restrict__ out1)
{
    const int tid  = threadIdx.x;
    const int wid  = tid >> 6, lane = tid & 63;
    const int m    = lane & 15, g = lane >> 4;
    const int job  = blockIdx.x * 2 + wid;          // 2048 jobs
    const int rt   = job >> 4;                      // 128 row-tiles
    const int nw   = rt * 16;
    const int o0   = (job & 15) * 16;               // 16 col-tiles

    // --- weight A-fragments (loop-invariant): 4 limbs x 4 chunks = 64 VGPRs
    intx4 bfrag[4][4];
#pragma unroll
    for (int l = 0; l < 4; ++l)
#pragma unroll
        for (int c = 0; c < 4; ++c)
            bfrag[l][c] = *(const intx4*)(Bw8 + ((size_t)(o0 + m) * 4 + l) * 256
                                               + c * 64 + g * 16);
    // per-lane bias for out-cols o0+4g .. o0+4g+3
    const float4 biasv = *(const float4*)(b_rnn + 256 + o0 + g * 4);

    // --- store base: spike-row nw+m, col o0+4g (16B-aligned) ---
    float* pb = out0 + ((size_t)(nw >> 5) * 96) * 8192
                     + (size_t)((nw & 31) + m) * 256 + o0 + g * 4;

    // --- mask stream: lane reads uint2 at row*32 + 8g, 3 steps in hand ---
    const unsigned char* mp = s0b + ((size_t)(nw + m)) * 32 + 8 * g;
    uint2 m0 = *(const uint2*)(mp);
    uint2 m1 = *(const uint2*)(mp + 65536);
    uint2 m2 = *(const uint2*)(mp + 2 * 65536);

    floatx4 v = {0.f, 0.f, 0.f, 0.f};

    #define STEP_MFMA(MASK, ACC0, ACC1, ACC2, ACC3)                            \
    do {                                                                       \
        unsigned int hw_[4] = { (MASK).x & 0xFFFFu, (MASK).x >> 16,            \
                                (MASK).y & 0xFFFFu, (MASK).y >> 16 };          \
        _Pragma("unroll")                                                      \
        for (int c = 0; c < 4; ++c) {                                          \
            unsigned int h_ = hw_[c];                                          \
            intx4 a_;                                                          \
            a_.x = (int)(__umul24( h_        & 0xFu, 0x00204081u) & 0x01010101u); \
            a_.y = (int)(__umul24((h_ >> 4)  & 0xFu, 0x00204081u) & 0x01010101u); \
            a_.z = (int)(__umul24((h_ >> 8)  & 0xFu, 0x00204081u) & 0x01010101u); \
            a_.w = (int)(__umul24((h_ >> 12) & 0xFu, 0x00204081u) & 0x01010101u); \
            ACC0 = __builtin_amdgcn_mfma_i32_16x16x64_i8(bfrag[0][c], a_, ACC0, 0, 0, 0); \
            ACC1 = __builtin_amdgcn_mfma_i32_16x16x64_i8(bfrag[1][c], a_, ACC1, 0, 0, 0); \
            ACC2 = __builtin_amdgcn_mfma_i32_16x16x64_i8(bfrag[2][c], a_, ACC2, 0, 0, 0); \
            ACC3 = __builtin_amdgcn_mfma_i32_16x16x64_i8(bfrag[3][c], a_, ACC3, 0, 0, 0); \
        }                                                                      \
    } while (0)

    #define MEMBRANE(ACC0, ACC1, ACC2, ACC3, SV)                               \
    do {                                                                       \
        _Pragma("unroll")                                                      \
        for (int r = 0; r < 4; ++r) {                                          \
            int a01 = (ACC0)[r] * 128 + (ACC1)[r];   /* exact, |.| < 2^22 */   \
            int a23 = (ACC2)[r] * 128 + (ACC3)[r];                             \
            float cur = fmaf((float)a01, 0x1p-13f, (float)a23 * 0x1p-27f)      \
                        + ((const float*)&biasv)[r];                           \
            float vv = v[r];                                                   \
            vv = vv + (cur - vv) * 0.5f;                                       \
            float s = ((vv - 1.0f) >= 0.0f) ? 1.0f : 0.0f;                     \
            v[r] = vv * (1.0f - s);                                            \
            (SV)[r] = s;                                                       \
        }                                                                      \
    } while (0)

    // groups (0..2)..(90..92); peeled (93..95)
    for (int t = 0; t < 93; t += 3) {
        uint2 p3 = *(const uint2*)(mp + (size_t)(t + 3) * 65536);
        uint2 p4 = *(const uint2*)(mp + (size_t)(t + 4) * 65536);
        uint2 p5 = *(const uint2*)(mp + (size_t)(t + 5) * 65536);

        intx4 aa0 = {0,0,0,0}, aa1 = {0,0,0,0}, aa2 = {0,0,0,0}, aa3 = {0,0,0,0};
        intx4 ba0 = {0,0,0,0}, ba1 = {0,0,0,0}, ba2 = {0,0,0,0}, ba3 = {0,0,0,0};
        intx4 ca0 = {0,0,0,0}, ca1 = {0,0,0,0}, ca2 = {0,0,0,0}, ca3 = {0,0,0,0};
        STEP_MFMA(m0, aa0, aa1, aa2, aa3);   // step t
        STEP_MFMA(m1, ba0, ba1, ba2, ba3);   // step t+1 (independent accs)
        STEP_MFMA(m2, ca0, ca1, ca2, ca3);   // step t+2 (independent accs)

        floatx4 sva, svb, svc;
        MEMBRANE(aa0, aa1, aa2, aa3, sva);
        *(floatx4*)pb = sva;
        MEMBRANE(ba0, ba1, ba2, ba3, svb);
        *(floatx4*)(pb + 8192) = svb;
        MEMBRANE(ca0, ca1, ca2, ca3, svc);
        *(floatx4*)(pb + 16384) = svc;

        pb += 24576;
        m0 = p3; m1 = p4; m2 = p5;
    }

    // --- peeled group t = 93, 94, 95 (masks already in m0, m1, m2) ---
    {
        intx4 aa0 = {0,0,0,0}, aa1 = {0,0,0,0}, aa2 = {0,0,0,0}, aa3 = {0,0,0,0};
        intx4 ba0 = {0,0,0,0}, ba1 = {0,0,0,0}, ba2 = {0,0,0,0}, ba3 = {0,0,0,0};
        intx4 ca0 = {0,0,0,0}, ca1 = {0,0,0,0}, ca2 = {0,0,0,0}, ca3 = {0,0,0,0};
        STEP_MFMA(m0, aa0, aa1, aa2, aa3);
        STEP_MFMA(m1, ba0, ba1, ba2, ba3);
        STEP_MFMA(m2, ca0, ca1, ca2, ca3);
        floatx4 sva, svb, svc;
        MEMBRANE(aa0, aa1, aa2, aa3, sva);
        *(floatx4*)pb = sva;
        MEMBRANE(ba0, ba1, ba2, ba3, svb);
        *(floatx4*)(pb + 8192) = svb;
        MEMBRANE(ca0, ca1, ca2, ca3, svc);
        *(floatx4*)(pb + 16384) = svc;
        *(floatx4*)(out1 + (size_t)(nw + m) * 256 + o0 + g * 4) = svc;
    }
    #undef STEP_MFMA
    #undef MEMBRANE
}

// ---------------------------------------------------------------------------
extern "C" void kernel_launch(void* const* d_in, const int* in_sizes, int n_in,
                              void* d_out, int out_size, void* d_ws, size_t ws_size,
                              hipStream_t stream) {
    const float* inputs = (const float*)d_in[0];   // [64,96,32]
    const float* w_enc  = (const float*)d_in[1];   // [256,1,3]
    const float* b_enc  = (const float*)d_in[2];   // [256]
    const float* w_rnn  = (const float*)d_in[3];   // [2,256,256]
    const float* b_rnn  = (const float*)d_in[4];   // [2,256]

    float* out0 = (float*)d_out;                       // [64,96,8192]
    float* out1 = out0 + (size_t)64 * 96 * 8192;       // [64,8192]

    char* ws = (char*)d_ws;
    double*      Wd  = (double*)(ws);                  //  768 doubles  [0,6144)
    double*      C0d = (double*)(ws + 6144);           //  256 doubles  [6144,8192)
    signed char* Bw8 = (signed char*)(ws + 8192);      //  256*4*256 i8 [8192,270336)
    unsigned char* s0b = (unsigned char*)(ws + 270336);// 98*65536 B spike bits (2 pad slots)

    prep_kernel<<<256, 64, 0, stream>>>(w_enc, b_enc, w_rnn, b_rnn, Wd, C0d, Bw8);
    enc_kernel<<<2048, 256, 0, stream>>>(inputs, Wd, C0d, s0b);
    rnn_kernel<<<1024, 128, 0, stream>>>(s0b, Bw8, b_rnn, out0, out1);
}

// Round 16
// 251.791 us; speedup vs baseline: 1.3292x; 1.0007x over previous
//
#include <hip/hip_runtime.h>
#include <hip/hip_bf16.h>
#include <stdint.h>

// Problem constants: B=64, L=96, C=32, H=256, NL=2, K=3, TAU=2, VTH=1
// n = b*32 + c indexes the B*C=2048 "rows"; layer width H=256.

using floatx4 = __attribute__((ext_vector_type(4))) float;
using intx4   = __attribute__((ext_vector_type(4))) int;

// ---------------------------------------------------------------------------
// prep: per output-neuron o (256 blocks x 64 threads)
//  - W[o][k]  = sum_i w0[o,i]*w_enc[i,k]   (fp64)
//  - C0[o]    = sum_i b_enc[i]*w0[o,i] + b_rnn[0][o]  (fp64)
//  - i8 4-limb digit planes of w1: q=rn(w*2^27), q=((d0*128+d1)*128+d2)*128+d3,
//    digits in [-64,63]. Bw8[o][l][k] = d_l of w1[o][k].
// ---------------------------------------------------------------------------
__global__ void prep_kernel(const float* __restrict__ w_enc,
                            const float* __restrict__ b_enc,
                            const float* __restrict__ w_rnn,
                            const float* __restrict__ b_rnn,
                            double* __restrict__ Wd,
                            double* __restrict__ C0d,
                            signed char* __restrict__ Bw8)
{
    const int o = blockIdx.x;
    const int lane = threadIdx.x;   // 64 threads
    const float4 w0v = *(const float4*)(w_rnn + (size_t)o * 256 + lane * 4);
    double a0 = 0.0, a1 = 0.0, a2 = 0.0, ab = 0.0;
#pragma unroll
    for (int e = 0; e < 4; ++e) {
        const int i = lane * 4 + e;
        const double wv = (double)(((const float*)&w0v)[e]);
        a0 += wv * (double)w_enc[i * 3 + 0];
        a1 += wv * (double)w_enc[i * 3 + 1];
        a2 += wv * (double)w_enc[i * 3 + 2];
        ab += wv * (double)b_enc[i];
    }
    for (int off = 32; off > 0; off >>= 1) {
        a0 += __shfl_down(a0, off, 64);
        a1 += __shfl_down(a1, off, 64);
        a2 += __shfl_down(a2, off, 64);
        ab += __shfl_down(ab, off, 64);
    }
    if (lane == 0) {
        Wd[o * 3 + 0] = a0;
        Wd[o * 3 + 1] = a1;
        Wd[o * 3 + 2] = a2;
        C0d[o] = ab + (double)b_rnn[o];
    }
    // i8 digit planes of w1 (layer-1), 4 consecutive k per lane
    const float4 w1v = *(const float4*)(w_rnn + 65536 + (size_t)o * 256 + lane * 4);
    unsigned int pack[4] = {0u, 0u, 0u, 0u};   // pack[l]: digits for e=0..3
#pragma unroll
    for (int e = 0; e < 4; ++e) {
        float f = ((const float*)&w1v)[e];
        int q = __double2int_rn((double)f * 134217728.0);   // w * 2^27, |q| <= 2^27
        int d3 = ((q + 64) & 127) - 64;  q = (q - d3) >> 7;
        int d2 = ((q + 64) & 127) - 64;  q = (q - d2) >> 7;
        int d1 = ((q + 64) & 127) - 64;  q = (q - d1) >> 7;
        int d0 = q;                       // |d0| <= 64
        pack[0] |= ((unsigned int)(d0 & 0xFF)) << (8 * e);
        pack[1] |= ((unsigned int)(d1 & 0xFF)) << (8 * e);
        pack[2] |= ((unsigned int)(d2 & 0xFF)) << (8 * e);
        pack[3] |= ((unsigned int)(d3 & 0xFF)) << (8 * e);
    }
#pragma unroll
    for (int l = 0; l < 4; ++l)
        *(unsigned int*)(Bw8 + ((size_t)o * 4 + l) * 256 + lane * 4) = pack[l];
}

// ---------------------------------------------------------------------------
// enc: layer-0 full scan. 2048 blocks x 256 threads. cur0 in fp64 (correctly
// rounded), membrane chain in exact reference fp32 op order. Spike mask rows
// stored HALFWORD-TRANSPOSED: row (t,n) is 32B; global halfword h=i/16
// (h = 4*wave + j) lands at byte offset 8*j + 2*wave -> rnn lane (g,m) reads
// one aligned uint2 at +8g = exactly the k-bits its 4 MFMA chunks need.
// ---------------------------------------------------------------------------
__global__ void enc_kernel(const float* __restrict__ inputs,
                           const double* __restrict__ Wd,
                           const double* __restrict__ C0d,
                           unsigned char* __restrict__ s0b)
{
    const int n = blockIdx.x;
    const int tidx = threadIdx.x;
    const int b = n >> 5, c = n & 31;
    __shared__ float xr[98];
    if (tidx < 96)       xr[tidx + 1] = inputs[((size_t)b * 96 + tidx) * 32 + c];
    else if (tidx == 96) xr[0]  = 0.0f;
    else if (tidx == 97) xr[97] = 0.0f;
    __syncthreads();
    const double W0 = Wd[tidx * 3], W1 = Wd[tidx * 3 + 1], W2 = Wd[tidx * 3 + 2];
    const double c0 = C0d[tidx];
    const int wid = tidx >> 6, lane = tidx & 63;
    float v = 0.0f;
    for (int t = 0; t < 96; ++t) {
        float cur = (float)((double)xr[t] * W0 + (double)xr[t + 1] * W1 +
                            (double)xr[t + 2] * W2 + c0);
        float vv = v + (cur - v) * 0.5f;
        int sp = (vv - 1.0f) >= 0.0f;
        v = sp ? 0.0f : vv;
        unsigned long long bal = __ballot(sp);
        if ((lane & 15) == 0) {
            const int j = lane >> 4;
            *(unsigned short*)(s0b + ((size_t)t * 2048 + n) * 32 + 8 * j + 2 * wid)
                = (unsigned short)(bal >> (16 * j));
        }
    }
}

// ---------------------------------------------------------------------------
// rnn: layer-1, i8 4-limb exact MFMA, NO LDS, NO barriers.
// R16 = R14 champion verbatim (3-deep pipeline; R15's 4-deep was zero-gain
// and tripped the post-timing check — reverted). 1024 blocks x 2 waves
// (128 thr, __launch_bounds__(128,2) -> 256-VGPR budget). Each iteration
// computes MFMAs for steps t, t+1, t+2 with INDEPENDENT accumulator sets
// (12 independent 4-MFMA chains live), so the matrix work of later steps
// (depends only on prefetched masks, not on v) overlaps earlier steps'
// membrane VALU + store drain. Bit-spread muls use __umul24 -> full-rate
// v_mul_u32_u24.
// Decision math BIT-IDENTICAL to R8/R13 per step: i8 limb MFMA (exact), fp32
// limb combine fmaf((float)a01, 2^-13, (float)a23*2^-27) == RN(exact sum);
// membrane in exact reference fp32 op order; vv*(1-s) hard reset.
// C/D 16x16: M=(lane>>4)*4+reg -> out-col; N=lane&15 -> spike-row.
// ---------------------------------------------------------------------------
__global__ __launch_bounds__(128, 2) void rnn_kernel(
    const unsigned char* __restrict__ s0b,
    const signed char* __restrict__ Bw8,
    const float* __restrict__ b_rnn,
    float* __restrict__ out0,
    float* __restrict__ out1)
{
    const int tid  = threadIdx.x;
    const int wid  = tid >> 6, lane = tid & 63;
    const int m    = lane & 15, g = lane >> 4;
    const int job  = blockIdx.x * 2 + wid;          // 2048 jobs
    const int rt   = job >> 4;                      // 128 row-tiles
    const int nw   = rt * 16;
    const int o0   = (job & 15) * 16;               // 16 col-tiles

    // --- weight A-fragments (loop-invariant): 4 limbs x 4 chunks = 64 VGPRs
    intx4 bfrag[4][4];
#pragma unroll
    for (int l = 0; l < 4; ++l)
#pragma unroll
        for (int c = 0; c < 4; ++c)
            bfrag[l][c] = *(const intx4*)(Bw8 + ((size_t)(o0 + m) * 4 + l) * 256
                                               + c * 64 + g * 16);
    // per-lane bias for out-cols o0+4g .. o0+4g+3
    const float4 biasv = *(const float4*)(b_rnn + 256 + o0 + g * 4);

    // --- store base: spike-row nw+m, col o0+4g (16B-aligned) ---
    float* pb = out0 + ((size_t)(nw >> 5) * 96) * 8192
                     + (size_t)((nw & 31) + m) * 256 + o0 + g * 4;

    // --- mask stream: lane reads uint2 at row*32 + 8g, 3 steps in hand ---
    const unsigned char* mp = s0b + ((size_t)(nw + m)) * 32 + 8 * g;
    uint2 m0 = *(const uint2*)(mp);
    uint2 m1 = *(const uint2*)(mp + 65536);
    uint2 m2 = *(const uint2*)(mp + 2 * 65536);

    floatx4 v = {0.f, 0.f, 0.f, 0.f};

    #define STEP_MFMA(MASK, ACC0, ACC1, ACC2, ACC3)                            \
    do {                                                                       \
        unsigned int hw_[4] = { (MASK).x & 0xFFFFu, (MASK).x >> 16,            \
                                (MASK).y & 0xFFFFu, (MASK).y >> 16 };          \
        _Pragma("unroll")                                                      \
        for (int c = 0; c < 4; ++c) {                                          \
            unsigned int h_ = hw_[c];                                          \
            intx4 a_;                                                          \
            a_.x = (int)(__umul24( h_        & 0xFu, 0x00204081u) & 0x01010101u); \
            a_.y = (int)(__umul24((h_ >> 4)  & 0xFu, 0x00204081u) & 0x01010101u); \
            a_.z = (int)(__umul24((h_ >> 8)  & 0xFu, 0x00204081u) & 0x01010101u); \
            a_.w = (int)(__umul24((h_ >> 12) & 0xFu, 0x00204081u) & 0x01010101u); \
            ACC0 = __builtin_amdgcn_mfma_i32_16x16x64_i8(bfrag[0][c], a_, ACC0, 0, 0, 0); \
            ACC1 = __builtin_amdgcn_mfma_i32_16x16x64_i8(bfrag[1][c], a_, ACC1, 0, 0, 0); \
            ACC2 = __builtin_amdgcn_mfma_i32_16x16x64_i8(bfrag[2][c], a_, ACC2, 0, 0, 0); \
            ACC3 = __builtin_amdgcn_mfma_i32_16x16x64_i8(bfrag[3][c], a_, ACC3, 0, 0, 0); \
        }                                                                      \
    } while (0)

    #define MEMBRANE(ACC0, ACC1, ACC2, ACC3, SV)                               \
    do {                                                                       \
        _Pragma("unroll")                                                      \
        for (int r = 0; r < 4; ++r) {                                          \
            int a01 = (ACC0)[r] * 128 + (ACC1)[r];   /* exact, |.| < 2^22 */   \
            int a23 = (ACC2)[r] * 128 + (ACC3)[r];                             \
            float cur = fmaf((float)a01, 0x1p-13f, (float)a23 * 0x1p-27f)      \
                        + ((const float*)&biasv)[r];                           \
            float vv = v[r];                                                   \
            vv = vv + (cur - vv) * 0.5f;                                       \
            float s = ((vv - 1.0f) >= 0.0f) ? 1.0f : 0.0f;                     \
            v[r] = vv * (1.0f - s);                                            \
            (SV)[r] = s;                                                       \
        }                                                                      \
    } while (0)

    // groups (0..2)..(90..92); peeled (93..95)
    for (int t = 0; t < 93; t += 3) {
        uint2 p3 = *(const uint2*)(mp + (size_t)(t + 3) * 65536);
        uint2 p4 = *(const uint2*)(mp + (size_t)(t + 4) * 65536);
        uint2 p5 = *(const uint2*)(mp + (size_t)(t + 5) * 65536);

        intx4 aa0 = {0,0,0,0}, aa1 = {0,0,0,0}, aa2 = {0,0,0,0}, aa3 = {0,0,0,0};
        intx4 ba0 = {0,0,0,0}, ba1 = {0,0,0,0}, ba2 = {0,0,0,0}, ba3 = {0,0,0,0};
        intx4 ca0 = {0,0,0,0}, ca1 = {0,0,0,0}, ca2 = {0,0,0,0}, ca3 = {0,0,0,0};
        STEP_MFMA(m0, aa0, aa1, aa2, aa3);   // step t
        STEP_MFMA(m1, ba0, ba1, ba2, ba3);   // step t+1 (independent accs)
        STEP_MFMA(m2, ca0, ca1, ca2, ca3);   // step t+2 (independent accs)

        floatx4 sva, svb, svc;
        MEMBRANE(aa0, aa1, aa2, aa3, sva);
        *(floatx4*)pb = sva;
        MEMBRANE(ba0, ba1, ba2, ba3, svb);
        *(floatx4*)(pb + 8192) = svb;
        MEMBRANE(ca0, ca1, ca2, ca3, svc);
        *(floatx4*)(pb + 16384) = svc;

        pb += 24576;
        m0 = p3; m1 = p4; m2 = p5;
    }

    // --- peeled group t = 93, 94, 95 (masks already in m0, m1, m2) ---
    {
        intx4 aa0 = {0,0,0,0}, aa1 = {0,0,0,0}, aa2 = {0,0,0,0}, aa3 = {0,0,0,0};
        intx4 ba0 = {0,0,0,0}, ba1 = {0,0,0,0}, ba2 = {0,0,0,0}, ba3 = {0,0,0,0};
        intx4 ca0 = {0,0,0,0}, ca1 = {0,0,0,0}, ca2 = {0,0,0,0}, ca3 = {0,0,0,0};
        STEP_MFMA(m0, aa0, aa1, aa2, aa3);
        STEP_MFMA(m1, ba0, ba1, ba2, ba3);
        STEP_MFMA(m2, ca0, ca1, ca2, ca3);
        floatx4 sva, svb, svc;
        MEMBRANE(aa0, aa1, aa2, aa3, sva);
        *(floatx4*)pb = sva;
        MEMBRANE(ba0, ba1, ba2, ba3, svb);
        *(floatx4*)(pb + 8192) = svb;
        MEMBRANE(ca0, ca1, ca2, ca3, svc);
        *(floatx4*)(pb + 16384) = svc;
        *(floatx4*)(out1 + (size_t)(nw + m) * 256 + o0 + g * 4) = svc;
    }
    #undef STEP_MFMA
    #undef MEMBRANE
}

// ---------------------------------------------------------------------------
extern "C" void kernel_launch(void* const* d_in, const int* in_sizes, int n_in,
                              void* d_out, int out_size, void* d_ws, size_t ws_size,
                              hipStream_t stream) {
    const float* inputs = (const float*)d_in[0];   // [64,96,32]
    const float* w_enc  = (const float*)d_in[1];   // [256,1,3]
    const float* b_enc  = (const float*)d_in[2];   // [256]
    const float* w_rnn  = (const float*)d_in[3];   // [2,256,256]
    const float* b_rnn  = (const float*)d_in[4];   // [2,256]

    float* out0 = (float*)d_out;                       // [64,96,8192]
    float* out1 = out0 + (size_t)64 * 96 * 8192;       // [64,8192]

    char* ws = (char*)d_ws;
    double*      Wd  = (double*)(ws);                  //  768 doubles  [0,6144)
    double*      C0d = (double*)(ws + 6144);           //  256 doubles  [6144,8192)
    signed char* Bw8 = (signed char*)(ws + 8192);      //  256*4*256 i8 [8192,270336)
    unsigned char* s0b = (unsigned char*)(ws + 270336);// 98*65536 B spike bits (2 pad slots)

    prep_kernel<<<256, 64, 0, stream>>>(w_enc, b_enc, w_rnn, b_rnn, Wd, C0d, Bw8);
    enc_kernel<<<2048, 256, 0, stream>>>(inputs, Wd, C0d, s0b);
    rnn_kernel<<<1024, 128, 0, stream>>>(s0b, Bw8, b_rnn, out0, out1);
}